// Round 2
// 15224.352 us; speedup vs baseline: 1.0175x; 1.0175x over previous
//
#include <hip/hip_runtime.h>
#include <cstddef>

// Problem constants (fixed by the reference).
#define BATCH   4096
#define NBLK    100
#define NSLOT   300
#define NSTATE  1436
#define HID     256
#define NSTEPS  100
#define NEGV    (-1000.0f)
#define KC      384      // OpenBLAS sgemm K-panel (SGEMM_DEFAULT_Q, haswell/zen)

// Bit-faithful *float32* path. Evidence (r2/r3 both absmax=24.0 bit-identical
// despite ulp-level loop changes) says the np reference is f32: any f64 impl
// lands on the exact-arithmetic trajectory, a fixed ~12-flip distance from the
// reference's own f32-noise trajectory. To pass we must reproduce numpy+
// OpenBLAS f32 rounding: ascending-k fma chains, KC=384 panel splits,
// separately-rounded bias adds, np op order in the LSTM pointwise, and
// near-correctly-rounded f32 exp/tanh (via f64 libm, rounded to f32).

__device__ __forceinline__ float sigf(float x) {
#pragma clang fp contract(off)
  float e = (float)exp(-(double)x);   // ~CR f32 exp
  float d = 1.0f + e;
  return 1.0f / d;                    // IEEE f32 divide (CR)
}
__device__ __forceinline__ float tanhf32(float x) {
  return (float)tanh((double)x);      // ~CR f32 tanh
}

// first-max argmax across a wave64; result broadcast to all lanes.
__device__ __forceinline__ void argmax64f(float& v, int& i) {
#pragma unroll
  for (int off = 32; off > 0; off >>= 1) {
    float v2 = __shfl_down(v, off, 64);
    int   i2 = __shfl_down(i, off, 64);
    if (v2 > v || (v2 == v && i2 < i)) { v = v2; i = i2; }
  }
  v = __shfl(v, 0, 64);
  i = __shfl(i, 0, 64);
}

// ---------------------------------------------------------------------------
// state concat (also the A-source for the first MLP GEMM)
// ---------------------------------------------------------------------------
__global__ __launch_bounds__(256) void concat_kernel(
    const float* __restrict__ to_t, const float* __restrict__ ti_t,
    const float* __restrict__ ys_t, float* __restrict__ state)
{
  int b = blockIdx.x;
  for (int li = threadIdx.x; li < 7180; li += 256) {
    float v = (li < 500)  ? to_t[(size_t)b * 500 + li]
            : (li < 1000) ? ti_t[(size_t)b * 500 + (li - 500)]
                          : ys_t[(size_t)b * 6180 + (li - 1000)];
    state[(size_t)b * 7180 + li] = v;
  }
}

// ---------------------------------------------------------------------------
// Generic f32 GEMM tile: C[64x64] = act(A @ W^T + bias)
// A f32 row-major [M,K] lda; W f32 row-major [N,K] ldw.
// Per element: ascending-k fmaf chain, panel commit every KC (sgemm order),
// then one rounded bias add.
// ---------------------------------------------------------------------------
__device__ __forceinline__ void gemm32_tile(
    const float* __restrict__ A, int lda,
    const float* __restrict__ W, int ldw,
    const float* __restrict__ bias,
    float* __restrict__ C, int ldc,
    int N, int K, int row0, int col0, bool relu)
{
#pragma clang fp contract(off)
  __shared__ float As[16][68];
  __shared__ float Ws[16][68];
  const int t = threadIdx.x;
  const int tx = t & 15, ty = t >> 4;
  const int mload = t >> 2;          // 0..63
  const int kq    = (t & 3) << 2;    // 0,4,8,12
  const int gn    = col0 + mload;
  const float* Aptr = A + (size_t)(row0 + mload) * lda + kq;
  const float* Wptr = (gn < N) ? (W + (size_t)gn * ldw + kq) : nullptr;

  float acc[4][4] = {};
  float res[4][4];
  bool first = true;
  for (int k0 = 0; k0 < K; k0 += 16) {
    if (k0 > 0 && (k0 % KC) == 0) {  // sgemm K-panel boundary: commit panel
#pragma unroll
      for (int i = 0; i < 4; i++)
#pragma unroll
        for (int j = 0; j < 4; j++) {
          res[i][j] = first ? acc[i][j] : (res[i][j] + acc[i][j]);
          acc[i][j] = 0.0f;
        }
      first = false;
    }
    float4 av = *(const float4*)(Aptr + k0);
    float4 wv = make_float4(0.f, 0.f, 0.f, 0.f);
    if (Wptr) wv = *(const float4*)(Wptr + k0);
    As[kq + 0][mload] = av.x; As[kq + 1][mload] = av.y;
    As[kq + 2][mload] = av.z; As[kq + 3][mload] = av.w;
    Ws[kq + 0][mload] = wv.x; Ws[kq + 1][mload] = wv.y;
    Ws[kq + 2][mload] = wv.z; Ws[kq + 3][mload] = wv.w;
    __syncthreads();
#pragma unroll
    for (int kk = 0; kk < 16; kk++) {
      float a[4], w[4];
#pragma unroll
      for (int i = 0; i < 4; i++) { a[i] = As[kk][ty * 4 + i]; w[i] = Ws[kk][tx * 4 + i]; }
#pragma unroll
      for (int i = 0; i < 4; i++)
#pragma unroll
        for (int j = 0; j < 4; j++) acc[i][j] = fmaf(a[i], w[j], acc[i][j]);
    }
    __syncthreads();
  }
#pragma unroll
  for (int i = 0; i < 4; i++)
#pragma unroll
    for (int j = 0; j < 4; j++)
      res[i][j] = first ? acc[i][j] : (res[i][j] + acc[i][j]);

#pragma unroll
  for (int i = 0; i < 4; i++) {
    size_t row = (size_t)(row0 + ty * 4 + i) * ldc;
#pragma unroll
    for (int j = 0; j < 4; j++) {
      int n = col0 + tx * 4 + j;
      if (n < N) {
        float v = res[i][j] + bias[n];
        if (relu) v = v > 0.0f ? v : 0.0f;
        C[row + n] = v;
      }
    }
  }
}

__global__ __launch_bounds__(256) void gemm32_kernel(
    const float* __restrict__ A, int lda, const float* __restrict__ W, int ldw,
    const float* __restrict__ bias, float* __restrict__ C, int ldc,
    int N, int K, int relu)
{
  gemm32_tile(A, lda, W, ldw, bias, C, ldc, N, K,
              blockIdx.y * 64, blockIdx.x * 64, relu != 0);
}

// ---------------------------------------------------------------------------
// GEMM1: X1[r, o] = relu( sum_n state[b, n, j] * W1[o, n] + b1[o] )
// R = row_base + r, b = R/5, j = R%5. K=1436 -> panels 384/384/384/284.
// ---------------------------------------------------------------------------
__global__ __launch_bounds__(256) void gemm1_kernel(
    const float* __restrict__ state, const float* __restrict__ W1,
    const float* __restrict__ b1, float* __restrict__ X1, int row_base)
{
#pragma clang fp contract(off)
  __shared__ float As[16][68];
  __shared__ float Ws[16][68];
  const int t = threadIdx.x;
  const int tx = t & 15, ty = t >> 4;
  const int mload = t >> 2;
  const int kq    = (t & 3) << 2;
  const int row0 = blockIdx.y * 64, col0 = blockIdx.x * 64;
  const int R = row_base + row0 + mload;
  const int b = R / 5, j = R - b * 5;
  const float* sp = state + (size_t)b * 7180 + j;
  const float* Wptr = W1 + (size_t)(col0 + mload) * NSTATE + kq;

  float acc[4][4] = {};
  float res[4][4];
  bool first = true;
  for (int k0 = 0; k0 < 1440; k0 += 16) {
    if (k0 == 384 || k0 == 768 || k0 == 1152) {
#pragma unroll
      for (int i = 0; i < 4; i++)
#pragma unroll
        for (int jj = 0; jj < 4; jj++) {
          res[i][jj] = first ? acc[i][jj] : (res[i][jj] + acc[i][jj]);
          acc[i][jj] = 0.0f;
        }
      first = false;
    }
    int n = k0 + kq;
    float a0 = (n + 0 < NSTATE) ? sp[(n + 0) * 5] : 0.0f;
    float a1 = (n + 1 < NSTATE) ? sp[(n + 1) * 5] : 0.0f;
    float a2 = (n + 2 < NSTATE) ? sp[(n + 2) * 5] : 0.0f;
    float a3 = (n + 3 < NSTATE) ? sp[(n + 3) * 5] : 0.0f;
    float4 wv = make_float4(0.f, 0.f, 0.f, 0.f);
    if (n + 3 < NSTATE) wv = *(const float4*)(Wptr + k0);
    As[kq + 0][mload] = a0; As[kq + 1][mload] = a1;
    As[kq + 2][mload] = a2; As[kq + 3][mload] = a3;
    Ws[kq + 0][mload] = wv.x; Ws[kq + 1][mload] = wv.y;
    Ws[kq + 2][mload] = wv.z; Ws[kq + 3][mload] = wv.w;
    __syncthreads();
#pragma unroll
    for (int kk = 0; kk < 16; kk++) {
      float a[4], w[4];
#pragma unroll
      for (int i = 0; i < 4; i++) { a[i] = As[kk][ty * 4 + i]; w[i] = Ws[kk][tx * 4 + i]; }
#pragma unroll
      for (int i = 0; i < 4; i++)
#pragma unroll
        for (int jj = 0; jj < 4; jj++) acc[i][jj] = fmaf(a[i], w[jj], acc[i][jj]);
    }
    __syncthreads();
  }
#pragma unroll
  for (int i = 0; i < 4; i++)
#pragma unroll
    for (int jj = 0; jj < 4; jj++)
      res[i][jj] = res[i][jj] + acc[i][jj];   // last (4th) panel commit

#pragma unroll
  for (int i = 0; i < 4; i++) {
    size_t row = (size_t)(row0 + ty * 4 + i) * 512;
#pragma unroll
    for (int jj = 0; jj < 4; jj++) {
      int n = col0 + tx * 4 + jj;
      float v = res[i][jj] + b1[n];
      X1[row + n] = v > 0.0f ? v : 0.0f;
    }
  }
}

// ---------------------------------------------------------------------------
// feat2: feat_vec[b,k] = sum_j X3[(bl*5+j),k]*W_fe2[j] + b_fe2 ; init h/c.
// ---------------------------------------------------------------------------
__global__ __launch_bounds__(256) void feat2c_kernel(
    const float* __restrict__ X3, const float* __restrict__ W_fe2,
    const float* __restrict__ b_fe2, float* __restrict__ hto,
    float* __restrict__ cto, float* __restrict__ hti, float* __restrict__ cti,
    int b_base)
{
#pragma clang fp contract(off)
  int bl = blockIdx.x, b = b_base + bl, k = threadIdx.x;
  float s = 0.0f;
#pragma unroll
  for (int j = 0; j < 5; j++)
    s = fmaf(X3[((size_t)bl * 5 + j) * 256 + k], W_fe2[j], s);
  float acc = s + b_fe2[0];
  hto[(size_t)b * 256 + k] = acc;
  hti[(size_t)b * 256 + k] = acc;
  cto[(size_t)b * 256 + k] = 0.0f;
  cti[(size_t)b * 256 + k] = 0.0f;
}

// ---------------------------------------------------------------------------
// init: mutable slots copy + masks + zero inp_buf
// ---------------------------------------------------------------------------
__global__ __launch_bounds__(320) void init_state_kernel(
    const float* __restrict__ to_t, const float* __restrict__ ti_t,
    const float* __restrict__ slot_info, float* __restrict__ slots,
    int* __restrict__ m_to, int* __restrict__ m_ti, float* __restrict__ inp)
{
  int b = blockIdx.x, t = threadIdx.x;
  for (int li = t; li < NSLOT * 5; li += 320)
    slots[(size_t)b * (NSLOT * 5) + li] = slot_info[(size_t)b * (NSLOT * 5) + li];
  if (t < NBLK) {
    m_to[b * 128 + t] = (to_t[(size_t)b * 500 + t * 5] != -1.0f) ? 1 : 0;
    m_ti[b * 128 + t] = (ti_t[(size_t)b * 500 + t * 5] != -1.0f) ? 1 : 0;
  }
  if (t < 8) inp[b * 8 + t] = 0.0f;
}

// init: concatenated logits weights [Wb;Ws] (exact copies)
__global__ __launch_bounds__(256) void init_weights_kernel(
    const float* __restrict__ Wb, const float* __restrict__ bb,
    const float* __restrict__ Ws, const float* __restrict__ bs,
    float* __restrict__ Wcat, float* __restrict__ bcat)
{
  int idx = blockIdx.x * 256 + threadIdx.x;
  if (idx < 400 * 256) {
    int n = idx / 256, k = idx % 256;
    Wcat[idx] = (n < 100) ? Wb[n * 256 + k] : Ws[(n - 100) * 256 + k];
  }
  if (idx < 400) bcat[idx] = (idx < 100) ? bb[idx] : bs[idx - 100];
}

// ---------------------------------------------------------------------------
// FUSED gates+LSTM, both LSTMs (blockIdx.z: 0=to, 1=ti).
// Tile: 128 batch rows x 32 units (=128 gate-columns). 256 threads; each
// thread owns 8 rows x 2 units x all 4 gates = 64 dot products of K=256.
//
// Bit-exactness: each gate pre-activation is the SAME ascending-k fmaf chain
// as the previous gates_kernel (K=256 < KC -> single panel), then the same
// epilogue rounding order: v1 = ih + bih; v2 = v1 + acc; v3 = v2 + bhh.
// The LSTM pointwise reproduces lstm32_kernel's op order exactly.
//
// LDS layout [k][col], stride 132 (128+4):
//   - compute w-reads: 16 consecutive words, 4-lane broadcast -> conflict-free
//   - compute a-reads: 2x b128, 4 addrs/wave broadcast      -> conflict-free
//   - staging writes: 2-way (free)
// h is ping-ponged by the host (other blocks still read h_old); c is updated
// in place (each (row,unit) cell is owned by exactly one thread).
// ---------------------------------------------------------------------------
__global__ __launch_bounds__(256) void gates_lstm_kernel(
    const float* __restrict__ hto_old, const float* __restrict__ hti_old,
    float* __restrict__ hto_new, float* __restrict__ hti_new,
    float* __restrict__ cto, float* __restrict__ cti,
    const float* __restrict__ Whh_to, const float* __restrict__ Whh_ti,
    const float* __restrict__ Wih_to, const float* __restrict__ Wih_ti,
    const float* __restrict__ bih_to, const float* __restrict__ bih_ti,
    const float* __restrict__ bhh_to, const float* __restrict__ bhh_ti,
    const float* __restrict__ inp)
{
#pragma clang fp contract(off)
  const int z = blockIdx.z;
  const float* h_old = z ? hti_old : hto_old;
  float* h_new = z ? hti_new : hto_new;
  float* cbuf  = z ? cti : cto;
  const float* Whh  = z ? Whh_ti : Whh_to;
  const float* Wih  = z ? Wih_ti : Wih_to;
  const float* bihp = z ? bih_ti : bih_to;
  const float* bhhp = z ? bhh_ti : bhh_to;

  const int u0   = blockIdx.x * 32;
  const int row0 = blockIdx.y * 128;
  const int t  = threadIdx.x;
  const int tx = t & 15, ty = t >> 4;

  __shared__ float As[16][132];
  __shared__ float Bs[16][132];

  // staging: thread covers (row/col p = pass*64 + t>>2) at k-quarter (t&3)*4
  const int q  = t >> 2;          // 0..63
  const int kq = (t & 3) << 2;    // 0,4,8,12
  const float* aptr[2];
  const float* wptr[2];
  int colp[2];
#pragma unroll
  for (int pass = 0; pass < 2; pass++) {
    const int p = pass * 64 + q;
    colp[pass] = p;
    aptr[pass] = h_old + (size_t)(row0 + p) * 256 + kq;
    // col p -> Whh row o: txp=p&15, m=p>>4, gate=m&3, uu=m>>2
    const int m = p >> 4;
    const int o = (m & 3) * 256 + u0 + ((m >> 2) << 4) + (p & 15);
    wptr[pass] = Whh + (size_t)o * 256 + kq;
  }

  float acc[8][8];   // [row i][m = uu*4+gate]
#pragma unroll
  for (int i = 0; i < 8; i++)
#pragma unroll
    for (int m = 0; m < 8; m++) acc[i][m] = 0.0f;

  for (int k0 = 0; k0 < 256; k0 += 16) {
    float4 av0 = *(const float4*)(aptr[0] + k0);
    float4 av1 = *(const float4*)(aptr[1] + k0);
    float4 wv0 = *(const float4*)(wptr[0] + k0);
    float4 wv1 = *(const float4*)(wptr[1] + k0);
    if (k0) __syncthreads();        // prior tile's reads done before overwrite
    As[kq + 0][colp[0]] = av0.x; As[kq + 1][colp[0]] = av0.y;
    As[kq + 2][colp[0]] = av0.z; As[kq + 3][colp[0]] = av0.w;
    As[kq + 0][colp[1]] = av1.x; As[kq + 1][colp[1]] = av1.y;
    As[kq + 2][colp[1]] = av1.z; As[kq + 3][colp[1]] = av1.w;
    Bs[kq + 0][colp[0]] = wv0.x; Bs[kq + 1][colp[0]] = wv0.y;
    Bs[kq + 2][colp[0]] = wv0.z; Bs[kq + 3][colp[0]] = wv0.w;
    Bs[kq + 0][colp[1]] = wv1.x; Bs[kq + 1][colp[1]] = wv1.y;
    Bs[kq + 2][colp[1]] = wv1.z; Bs[kq + 3][colp[1]] = wv1.w;
    __syncthreads();
#pragma unroll
    for (int kk = 0; kk < 16; kk++) {
      float a[8], w[8];
#pragma unroll
      for (int i = 0; i < 8; i++) a[i] = As[kk][ty * 8 + i];
#pragma unroll
      for (int m = 0; m < 8; m++) w[m] = Bs[kk][m * 16 + tx];
#pragma unroll
      for (int i = 0; i < 8; i++)
#pragma unroll
        for (int m = 0; m < 8; m++)
          acc[i][m] = fmaf(a[i], w[m], acc[i][m]);
    }
  }

  // Epilogue: exact gates_kernel + lstm32_kernel arithmetic, fused.
  const int urow = row0 + ty * 8;
#pragma unroll
  for (int i = 0; i < 8; i++) {
    const int r = urow + i;
    float x0 = 0.f, x1 = 0.f, x2 = 0.f, x3 = 0.f, x4 = 0.f;
    if (!z) {
      const float* xp = inp + r * 8;
      x0 = xp[0]; x1 = xp[1]; x2 = xp[2]; x3 = xp[3]; x4 = xp[4];
    }
#pragma unroll
    for (int uu = 0; uu < 2; uu++) {
      const int u = u0 + uu * 16 + tx;
      float v[4];
#pragma unroll
      for (int g = 0; g < 4; g++) {
        const int o = g * 256 + u;
        const float* wp = Wih + o * 5;
        float ih = 0.0f;
        ih = fmaf(x0, wp[0], ih);
        ih = fmaf(x1, wp[1], ih);
        ih = fmaf(x2, wp[2], ih);
        ih = fmaf(x3, wp[3], ih);
        ih = fmaf(x4, wp[4], ih);
        float v1 = ih + bihp[o];           // x@Wih.T + bih   (rounded)
        float v2 = v1 + acc[i][uu * 4 + g];// ... + h@Whh.T   (rounded)
        v[g] = v2 + bhhp[o];               // ... + bhh       (rounded)
      }
      const size_t ci = (size_t)r * 256 + u;
      float sf = sigf(v[1]);
      float si = sigf(v[0]);
      float tg = tanhf32(v[2]);
      float t2 = sf * cbuf[ci];            // rounded mul
      float t5 = si * tg;                  // rounded mul
      float cc = t2 + t5;                  // rounded add
      cbuf[ci] = cc;
      float so = sigf(v[3]);
      float tc = tanhf32(cc);
      h_new[ci] = so * tc;
    }
  }
}

// logits. L[b,0:400] = h_to @ [Wb;Ws]^T + [bb;bs] ; L[b,400:500] = h_ti @ Wb^T + bb
__global__ __launch_bounds__(256) void logits32_kernel(
    const float* __restrict__ hto, const float* __restrict__ hti,
    const float* __restrict__ Wcat, const float* __restrict__ bcat,
    const float* __restrict__ Wb, const float* __restrict__ bb,
    float* __restrict__ L)
{
  int ct = blockIdx.x;              // 0..8
  if (ct < 7)
    gemm32_tile(hto, 256, Wcat, 256, bcat, L, 512, 400, 256,
                blockIdx.y * 64, ct * 64, false);
  else
    gemm32_tile(hti, 256, Wb, 256, bb, L + 400, 512, 100, 256,
                blockIdx.y * 64, (ct - 7) * 64, false);
}

// per-batch selection + state updates (one wave64 per batch row)
__global__ __launch_bounds__(64) void select32_kernel(
    const float* __restrict__ L, const float* __restrict__ to_t,
    int* __restrict__ m_to, int* __restrict__ m_ti, float* __restrict__ slots,
    float* __restrict__ inp, float* __restrict__ out_act, int step)
{
  int b = blockIdx.x, lane = threadIdx.x;
  const float* Lr = L + (size_t)b * 512;

  // block argmax (mask m_to)
  float bv = -3.4e38f; int bi = 0x7fffffff;
  for (int n = lane; n < NBLK; n += 64) {
    float v = m_to[b * 128 + n] ? Lr[n] : NEGV;
    if (v > bv) { bv = v; bi = n; }
  }
  argmax64f(bv, bi);
  int sel_b = bi;
  const float* blk = to_t + (size_t)b * 500 + sel_b * 5;
  float i0 = blk[0], i1 = blk[1];
  if (lane == 0) m_to[b * 128 + sel_b] = 0;
  if (lane < 5) inp[b * 8 + lane] = blk[lane];

  // slot argmax
  float sv = -3.4e38f; int si = 0x7fffffff;
  float* sl = slots + (size_t)b * (NSLOT * 5);
  for (int s = lane; s < NSLOT; s += 64) {
    float l = sl[s * 5 + 0], w = sl[s * 5 + 1];
    bool mask = (i0 >= l) || (i1 >= w) || (l == 0.0f);
    float v = mask ? NEGV : Lr[100 + s];
    if (v > sv) { sv = v; si = s; }
  }
  argmax64f(sv, si);
  int sel_s = si;
  if (lane == 0) {
    float c = sl[sel_s * 5 + 4] - 1.0f;
    if (c == 0.0f) {
      sl[sel_s * 5 + 0] = 0.f; sl[sel_s * 5 + 1] = 0.f; sl[sel_s * 5 + 2] = 0.f;
      sl[sel_s * 5 + 3] = 0.f; sl[sel_s * 5 + 4] = 0.f;
    } else {
      sl[sel_s * 5 + 4] = c;
    }
  }

  // ti block argmax (mask m_ti)
  float tv = -3.4e38f; int tii = 0x7fffffff;
  for (int n = lane; n < NBLK; n += 64) {
    float v = m_ti[b * 128 + n] ? Lr[400 + n] : NEGV;
    if (v > tv) { tv = v; tii = n; }
  }
  argmax64f(tv, tii);
  if (lane == 0) {
    m_ti[b * 128 + tii] = 0;
    float* oa = out_act + (size_t)b * (NSTEPS * 3) + step * 3;
    oa[0] = (float)sel_b; oa[1] = (float)sel_s; oa[2] = (float)tii;
  }
}

// ---------------------------------------------------------------------------
extern "C" void kernel_launch(void* const* d_in, const int* in_sizes, int n_in,
                              void* d_out, int out_size, void* d_ws, size_t ws_size,
                              hipStream_t stream) {
  (void)in_sizes; (void)n_in; (void)out_size; (void)ws_size;
  const float* to_t   = (const float*)d_in[0];
  const float* ti_t   = (const float*)d_in[1];
  const float* ys_t   = (const float*)d_in[2];
  const float* slot_i = (const float*)d_in[3];
  const float* W1 = (const float*)d_in[4];  const float* b1 = (const float*)d_in[5];
  const float* W2 = (const float*)d_in[6];  const float* b2 = (const float*)d_in[7];
  const float* W3 = (const float*)d_in[8];  const float* b3 = (const float*)d_in[9];
  const float* W_fe2 = (const float*)d_in[10]; const float* b_fe2 = (const float*)d_in[11];
  const float* Wih_to = (const float*)d_in[12]; const float* Whh_to = (const float*)d_in[13];
  const float* bih_to = (const float*)d_in[14]; const float* bhh_to = (const float*)d_in[15];
  const float* Wih_ti = (const float*)d_in[16]; const float* Whh_ti = (const float*)d_in[17];
  const float* bih_ti = (const float*)d_in[18]; const float* bhh_ti = (const float*)d_in[19];
  const float* Wb = (const float*)d_in[20]; const float* bb = (const float*)d_in[21];
  const float* Ws = (const float*)d_in[22]; const float* bs = (const float*)d_in[23];

  float* outf      = (float*)d_out;
  float* state_out = outf;                               // 4096*1436*5 f32
  float* out_act   = outf + (size_t)BATCH * NSTATE * 5;  // 4096*100*3  f32

  // Workspace layout in floats (peak 16,896,400 floats ~= 67.6 MB, under the
  // previous 71.3 MB layout). g buffer eliminated (fused gates+lstm); h is
  // double-buffered per LSTM for the ping-pong.
  float* ws = (float*)d_ws;
  float* X1 = ws;                      // 2560*512 = 1,310,720 (feature phase)
  float* X2 = ws + 1310720;            // 1,310,720
  float* X3 = ws + 2621440;            //   655,360 -> feature scratch ends 3,276,800
  float* Lb = ws;                      // 4096*512 = 2,097,152 (decode, overlaps X1/X2)
  float* hto0 = ws + 3276800;          // 4096*256 = 1,048,576 each
  float* hto1 = ws + 4325376;
  float* hti0 = ws + 5373952;
  float* hti1 = ws + 6422528;
  float* cto  = ws + 7471104;
  float* cti  = ws + 8519680;
  float* slots = ws + 9568256;         // 4096*1500 = 6,144,000
  int*   m_to  = (int*)(ws + 15712256);// 4096*128 ints
  int*   m_ti  = (int*)(ws + 16236544);
  float* inp_buf = ws + 16760832;      // 4096*8 = 32,768
  float* Wcat  = ws + 16793600;        // 400*256 = 102,400
  float* bcat  = ws + 16896000;        // 400

  concat_kernel<<<dim3(BATCH), 256, 0, stream>>>(to_t, ti_t, ys_t, state_out);
  init_state_kernel<<<dim3(BATCH), 320, 0, stream>>>(to_t, ti_t, slot_i, slots,
                                                     m_to, m_ti, inp_buf);
  init_weights_kernel<<<dim3(400), 256, 0, stream>>>(Wb, bb, Ws, bs, Wcat, bcat);

  // Feature MLP in 8 row-chunks of 2560 (512 batches each), f32 sgemm order.
  for (int c = 0; c < 8; c++) {
    int rb = c * 2560, b0 = c * 512;
    gemm1_kernel<<<dim3(8, 40), 256, 0, stream>>>(state_out, W1, b1, X1, rb);
    gemm32_kernel<<<dim3(8, 40), 256, 0, stream>>>(X1, 512, W2, 512, b2,
                                                   X2, 512, 512, 512, 1);
    gemm32_kernel<<<dim3(4, 40), 256, 0, stream>>>(X2, 512, W3, 512, b3,
                                                   X3, 256, 256, 512, 1);
    feat2c_kernel<<<dim3(512), 256, 0, stream>>>(X3, W_fe2, b_fe2,
                                                 hto0, cto, hti0, cti, b0);
  }

  // Sequential decode loop: 3 launches/step, h ping-pong.
  float* hto_o = hto0; float* hto_n = hto1;
  float* hti_o = hti0; float* hti_n = hti1;
  for (int s = 0; s < NSTEPS; s++) {
    gates_lstm_kernel<<<dim3(8, 32, 2), 256, 0, stream>>>(
        hto_o, hti_o, hto_n, hti_n, cto, cti,
        Whh_to, Whh_ti, Wih_to, Wih_ti,
        bih_to, bih_ti, bhh_to, bhh_ti, inp_buf);
    logits32_kernel<<<dim3(9, 64), 256, 0, stream>>>(hto_n, hti_n, Wcat, bcat,
                                                     Wb, bb, Lb);
    select32_kernel<<<dim3(BATCH), 64, 0, stream>>>(Lb, to_t, m_to, m_ti, slots,
                                                    inp_buf, out_act, s);
    float* tmp;
    tmp = hto_o; hto_o = hto_n; hto_n = tmp;
    tmp = hti_o; hti_o = hti_n; hti_n = tmp;
  }
}